// Round 1
// baseline (222.659 us; speedup 1.0000x reference)
//
#include <hip/hip_runtime.h>

// PrototypeClassifier: B=262144, P=512, D=40, O=256
// xmat[i,p] = dist[i] (scalar broadcast), out[i,o] = dist[i]*Wsum[o] + b[o]
// dist[i] = sqrt(512*||x_i||^2 - 2*x_i.proto_sum + ||proto||_F^2)

#define B_ROWS 262144
#define P_N 512
#define D_N 40
#define O_N 256

// ws layout (floats): [0,40) proto_sum, [40,296) Wsum, [296,336) per-dim proto sum-of-squares

__global__ __launch_bounds__(256) void pre_kernel(const float* __restrict__ proto,
                                                  const float* __restrict__ W,
                                                  float* __restrict__ ws) {
    __shared__ float sm[4];
    const int t = threadIdx.x;
    const int blk = blockIdx.x;
    const int lane = t & 63, w = t >> 6;
    if (blk < D_N) {
        // column sum + column sum-of-squares of prototypes[512][40]
        float s = 0.f, sq = 0.f;
        for (int p = t; p < P_N; p += 256) {
            float v = proto[p * D_N + blk];
            s += v;
            sq += v * v;
        }
        #pragma unroll
        for (int off = 32; off; off >>= 1) {
            s += __shfl_xor(s, off);
            sq += __shfl_xor(sq, off);
        }
        if (lane == 0) sm[w] = s;
        __syncthreads();
        if (t == 0) ws[blk] = sm[0] + sm[1] + sm[2] + sm[3];
        __syncthreads();
        if (lane == 0) sm[w] = sq;
        __syncthreads();
        if (t == 0) ws[296 + blk] = sm[0] + sm[1] + sm[2] + sm[3];
    } else {
        // row sum of W[256][512]
        const int o = blk - D_N;
        float s = 0.f;
        for (int p = t; p < P_N; p += 256) s += W[(long)o * P_N + p];
        #pragma unroll
        for (int off = 32; off; off >>= 1) s += __shfl_xor(s, off);
        if (lane == 0) sm[w] = s;
        __syncthreads();
        if (t == 0) ws[40 + o] = sm[0] + sm[1] + sm[2] + sm[3];
    }
}

__global__ __launch_bounds__(256) void main_kernel(const float* __restrict__ x,
                                                   const float* __restrict__ b,
                                                   const float* __restrict__ ws,
                                                   float* __restrict__ xmat,
                                                   float* __restrict__ outp) {
    __shared__ float s_psum[64];
    __shared__ float s_wsum[256];
    __shared__ float s_b[256];
    __shared__ float s_psq;
    const int t = threadIdx.x;
    if (t < 64) s_psum[t] = (t < D_N) ? ws[t] : 0.f;
    s_wsum[t] = ws[40 + t];
    s_b[t] = b[t];
    if (t < 64) {
        float v = (t < D_N) ? ws[296 + t] : 0.f;
        #pragma unroll
        for (int off = 32; off; off >>= 1) v += __shfl_xor(v, off);
        if (t == 0) s_psq = v;
    }
    __syncthreads();

    const float psq = s_psq;
    const int wave = t >> 6, lane = t & 63;
    const float ps = s_psum[lane];
    const float4 wv = reinterpret_cast<const float4*>(s_wsum)[lane];
    const float4 bv = reinterpret_cast<const float4*>(s_b)[lane];

    const long base_row = (long)blockIdx.x * 16 + (long)wave * 4;
    #pragma unroll
    for (int r = 0; r < 4; ++r) {
        const long row = base_row + r;
        const float xv = (lane < D_N) ? x[row * D_N + lane] : 0.f;
        float a = xv * xv;
        float c = xv * ps;
        #pragma unroll
        for (int off = 1; off < 64; off <<= 1) {
            a += __shfl_xor(a, off);
            c += __shfl_xor(c, off);
        }
        const float dist = sqrtf(fmaf(512.f, a, fmaf(-2.f, c, psq)));

        // xmat row: 512 identical floats, 2 x float4 per lane, fully coalesced
        const float4 dv = make_float4(dist, dist, dist, dist);
        float4* xm = reinterpret_cast<float4*>(xmat + row * (long)P_N);
        xm[lane * 2] = dv;
        xm[lane * 2 + 1] = dv;

        // out row: dist*Wsum + b, 1 x float4 per lane
        const float4 ov = make_float4(fmaf(dist, wv.x, bv.x), fmaf(dist, wv.y, bv.y),
                                      fmaf(dist, wv.z, bv.z), fmaf(dist, wv.w, bv.w));
        reinterpret_cast<float4*>(outp + row * (long)O_N)[lane] = ov;
    }
}

extern "C" void kernel_launch(void* const* d_in, const int* in_sizes, int n_in,
                              void* d_out, int out_size, void* d_ws, size_t ws_size,
                              hipStream_t stream) {
    const float* inp   = (const float*)d_in[0];
    const float* proto = (const float*)d_in[1];
    const float* W     = (const float*)d_in[2];
    const float* b     = (const float*)d_in[3];
    float* ws   = (float*)d_ws;
    float* xmat = (float*)d_out;
    float* outp = xmat + (long)B_ROWS * P_N;

    hipLaunchKernelGGL(pre_kernel, dim3(296), dim3(256), 0, stream, proto, W, ws);
    hipLaunchKernelGGL(main_kernel, dim3(B_ROWS / 16), dim3(256), 0, stream,
                       inp, b, ws, xmat, outp);
}

// Round 2
// 164.806 us; speedup vs baseline: 1.3510x; 1.3510x over previous
//
#include <hip/hip_runtime.h>

// PrototypeClassifier: B=262144, P=512, D=40, O=256
// xmat[i,p] = dist[i] (scalar broadcast), out[i,o] = dist[i]*Wsum[o] + b[o]
// dist[i] = sqrt(512*||x_i||^2 - 2*x_i.proto_sum + ||proto||_F^2)

#define B_ROWS 262144
#define P_N 512
#define D_N 40
#define O_N 256

// ws layout (floats): [0,40) proto_sum, [40,296) Wsum, [296,336) per-dim proto sum-of-squares

__global__ __launch_bounds__(256) void pre_kernel(const float* __restrict__ proto,
                                                  const float* __restrict__ W,
                                                  float* __restrict__ ws) {
    __shared__ float sm[4];
    const int t = threadIdx.x;
    const int blk = blockIdx.x;
    const int lane = t & 63, w = t >> 6;
    if (blk < D_N) {
        // column sum + column sum-of-squares of prototypes[512][40]
        float s = 0.f, sq = 0.f;
        for (int p = t; p < P_N; p += 256) {
            float v = proto[p * D_N + blk];
            s += v;
            sq += v * v;
        }
        #pragma unroll
        for (int off = 32; off; off >>= 1) {
            s += __shfl_xor(s, off);
            sq += __shfl_xor(sq, off);
        }
        if (lane == 0) sm[w] = s;
        __syncthreads();
        if (t == 0) ws[blk] = sm[0] + sm[1] + sm[2] + sm[3];
        __syncthreads();
        if (lane == 0) sm[w] = sq;
        __syncthreads();
        if (t == 0) ws[296 + blk] = sm[0] + sm[1] + sm[2] + sm[3];
    } else {
        // row sum of W[256][512]
        const int o = blk - D_N;
        float s = 0.f;
        for (int p = t; p < P_N; p += 256) s += W[(long)o * P_N + p];
        #pragma unroll
        for (int off = 32; off; off >>= 1) s += __shfl_xor(s, off);
        if (lane == 0) sm[w] = s;
        __syncthreads();
        if (t == 0) ws[40 + o] = sm[0] + sm[1] + sm[2] + sm[3];
    }
}

// One block = 256 rows. Phase 1: each thread computes dist for its own row
// (no cross-lane ops). Phase 2: block streams its contiguous 768 KB output
// region with unit-stride float4 stores (fill-kernel pattern).
__global__ __launch_bounds__(256) void main_kernel(const float* __restrict__ x,
                                                   const float* __restrict__ b,
                                                   const float* __restrict__ ws,
                                                   float* __restrict__ xmat,
                                                   float* __restrict__ outp) {
    __shared__ float sdist[256];
    const int t = threadIdx.x;
    const long base = (long)blockIdx.x * 256;

    // --- phase 1: per-thread dist ---
    const float4* __restrict__ xr  = reinterpret_cast<const float4*>(x + (base + t) * D_N);
    const float4* __restrict__ ps4 = reinterpret_cast<const float4*>(ws);        // proto_sum
    const float4* __restrict__ pq4 = reinterpret_cast<const float4*>(ws + 296);  // per-dim sq
    float sumsq = 0.f, dot = 0.f, psq = 0.f;
    #pragma unroll
    for (int k = 0; k < D_N / 4; ++k) {
        const float4 v = xr[k];
        const float4 p = ps4[k];
        const float4 q = pq4[k];
        sumsq = fmaf(v.x, v.x, fmaf(v.y, v.y, fmaf(v.z, v.z, fmaf(v.w, v.w, sumsq))));
        dot   = fmaf(v.x, p.x, fmaf(v.y, p.y, fmaf(v.z, p.z, fmaf(v.w, p.w, dot))));
        psq  += q.x + q.y + q.z + q.w;
    }
    sdist[t] = sqrtf(fmaf(512.f, sumsq, fmaf(-2.f, dot, psq)));
    __syncthreads();

    // --- phase 2a: xmat, 256 rows x 512 floats = 32768 contiguous float4 ---
    float4* __restrict__ xm = reinterpret_cast<float4*>(xmat + base * P_N);
    #pragma unroll 8
    for (int i = 0; i < 128; ++i) {
        const int j = i * 256 + t;            // row = j>>7, wave-uniform -> LDS broadcast
        const float d = sdist[j >> 7];
        xm[j] = make_float4(d, d, d, d);
    }

    // --- phase 2b: out, 256 rows x 256 floats = 16384 contiguous float4 ---
    const float4 wv = reinterpret_cast<const float4*>(ws + 40)[t & 63];
    const float4 bv = reinterpret_cast<const float4*>(b)[t & 63];
    float4* __restrict__ om = reinterpret_cast<float4*>(outp + base * O_N);
    #pragma unroll 8
    for (int i = 0; i < 64; ++i) {
        const int j = i * 256 + t;            // row = j>>6, wave-uniform -> LDS broadcast
        const float d = sdist[j >> 6];
        om[j] = make_float4(fmaf(d, wv.x, bv.x), fmaf(d, wv.y, bv.y),
                            fmaf(d, wv.z, bv.z), fmaf(d, wv.w, bv.w));
    }
}

extern "C" void kernel_launch(void* const* d_in, const int* in_sizes, int n_in,
                              void* d_out, int out_size, void* d_ws, size_t ws_size,
                              hipStream_t stream) {
    const float* inp   = (const float*)d_in[0];
    const float* proto = (const float*)d_in[1];
    const float* W     = (const float*)d_in[2];
    const float* b     = (const float*)d_in[3];
    float* ws   = (float*)d_ws;
    float* xmat = (float*)d_out;
    float* outp = xmat + (long)B_ROWS * P_N;

    hipLaunchKernelGGL(pre_kernel, dim3(296), dim3(256), 0, stream, proto, W, ws);
    hipLaunchKernelGGL(main_kernel, dim3(B_ROWS / 256), dim3(256), 0, stream,
                       inp, b, ws, xmat, outp);
}

// Round 3
// 162.614 us; speedup vs baseline: 1.3693x; 1.0135x over previous
//
#include <hip/hip_runtime.h>

// PrototypeClassifier: B=262144, P=512, D=40, O=256
// xmat[i,p] = dist[i] (scalar broadcast), out[i,o] = dist[i]*Wsum[o] + b[o]
// dist[i] = sqrt(512*||x_i||^2 - 2*x_i.proto_sum + ||proto||_F^2)

#define B_ROWS 262144
#define P_N 512
#define D_N 40
#define O_N 256

// ws layout (floats): [0,40) proto_sum, [40,296) Wsum, [296,336) per-dim proto
// sum-of-squares, [512, 512+B) dist (split path only)

__global__ __launch_bounds__(256) void pre_kernel(const float* __restrict__ proto,
                                                  const float* __restrict__ W,
                                                  float* __restrict__ ws) {
    __shared__ float sm[4];
    const int t = threadIdx.x;
    const int blk = blockIdx.x;
    const int lane = t & 63, w = t >> 6;
    if (blk < D_N) {
        float s = 0.f, sq = 0.f;
        for (int p = t; p < P_N; p += 256) {
            float v = proto[p * D_N + blk];
            s += v;
            sq += v * v;
        }
        #pragma unroll
        for (int off = 32; off; off >>= 1) {
            s += __shfl_xor(s, off);
            sq += __shfl_xor(sq, off);
        }
        if (lane == 0) sm[w] = s;
        __syncthreads();
        if (t == 0) ws[blk] = sm[0] + sm[1] + sm[2] + sm[3];
        __syncthreads();
        if (lane == 0) sm[w] = sq;
        __syncthreads();
        if (t == 0) ws[296 + blk] = sm[0] + sm[1] + sm[2] + sm[3];
    } else {
        const int o = blk - D_N;
        float s = 0.f;
        for (int p = t; p < P_N; p += 256) s += W[(long)o * P_N + p];
        #pragma unroll
        for (int off = 32; off; off >>= 1) s += __shfl_xor(s, off);
        if (lane == 0) sm[w] = s;
        __syncthreads();
        if (t == 0) ws[40 + o] = sm[0] + sm[1] + sm[2] + sm[3];
    }
}

// one thread = one row's dist
__global__ __launch_bounds__(256) void dist_kernel(const float* __restrict__ x,
                                                   const float* __restrict__ ws,
                                                   float* __restrict__ dist) {
    const long i = (long)blockIdx.x * 256 + threadIdx.x;
    const float4* __restrict__ xr  = reinterpret_cast<const float4*>(x + i * D_N);
    const float4* __restrict__ ps4 = reinterpret_cast<const float4*>(ws);
    const float4* __restrict__ pq4 = reinterpret_cast<const float4*>(ws + 296);
    float sumsq = 0.f, dot = 0.f, psq = 0.f;
    #pragma unroll
    for (int k = 0; k < D_N / 4; ++k) {
        const float4 v = xr[k];
        const float4 p = ps4[k];
        const float4 q = pq4[k];
        sumsq = fmaf(v.x, v.x, fmaf(v.y, v.y, fmaf(v.z, v.z, fmaf(v.w, v.w, sumsq))));
        dot   = fmaf(v.x, p.x, fmaf(v.y, p.y, fmaf(v.z, p.z, fmaf(v.w, p.w, dot))));
        psq  += q.x + q.y + q.z + q.w;
    }
    dist[i] = sqrtf(fmaf(512.f, sumsq, fmaf(-2.f, dot, psq)));
}

// pure streamer: block owns 128 contiguous rows; phase-1 is one 512 B load
__global__ __launch_bounds__(256) void stream_kernel(const float* __restrict__ b,
                                                     const float* __restrict__ ws,
                                                     const float* __restrict__ dist,
                                                     float* __restrict__ xmat,
                                                     float* __restrict__ outp) {
    __shared__ float sd[128];
    const int t = threadIdx.x;
    const long rbase = (long)blockIdx.x * 128;
    if (t < 32)
        reinterpret_cast<float4*>(sd)[t] =
            reinterpret_cast<const float4*>(dist + rbase)[t];
    const float4 wv = reinterpret_cast<const float4*>(ws + 40)[t & 63];
    const float4 bv = reinterpret_cast<const float4*>(b)[t & 63];
    __syncthreads();

    // xmat: 128 rows x 128 float4 = 16384 float4, unit-stride across block
    float4* __restrict__ xm = reinterpret_cast<float4*>(xmat + rbase * P_N);
    #pragma unroll 8
    for (int i = 0; i < 64; ++i) {
        const int j = i * 256 + t;           // row = j>>7, wave-uniform
        const float d = sd[j >> 7];
        xm[j] = make_float4(d, d, d, d);
    }

    // out: 128 rows x 64 float4 = 8192 float4
    float4* __restrict__ om = reinterpret_cast<float4*>(outp + rbase * O_N);
    #pragma unroll 8
    for (int i = 0; i < 32; ++i) {
        const int j = i * 256 + t;           // row = j>>6, wave-uniform
        const float d = sd[j >> 6];
        om[j] = make_float4(fmaf(d, wv.x, bv.x), fmaf(d, wv.y, bv.y),
                            fmaf(d, wv.z, bv.z), fmaf(d, wv.w, bv.w));
    }
}

// fallback: fused single-pass (used only if ws too small for dist array)
__global__ __launch_bounds__(256) void fused_kernel(const float* __restrict__ x,
                                                    const float* __restrict__ b,
                                                    const float* __restrict__ ws,
                                                    float* __restrict__ xmat,
                                                    float* __restrict__ outp) {
    __shared__ float sdist[256];
    const int t = threadIdx.x;
    const long base = (long)blockIdx.x * 256;
    const float4* __restrict__ xr  = reinterpret_cast<const float4*>(x + (base + t) * D_N);
    const float4* __restrict__ ps4 = reinterpret_cast<const float4*>(ws);
    const float4* __restrict__ pq4 = reinterpret_cast<const float4*>(ws + 296);
    float sumsq = 0.f, dot = 0.f, psq = 0.f;
    #pragma unroll
    for (int k = 0; k < D_N / 4; ++k) {
        const float4 v = xr[k];
        const float4 p = ps4[k];
        const float4 q = pq4[k];
        sumsq = fmaf(v.x, v.x, fmaf(v.y, v.y, fmaf(v.z, v.z, fmaf(v.w, v.w, sumsq))));
        dot   = fmaf(v.x, p.x, fmaf(v.y, p.y, fmaf(v.z, p.z, fmaf(v.w, p.w, dot))));
        psq  += q.x + q.y + q.z + q.w;
    }
    sdist[t] = sqrtf(fmaf(512.f, sumsq, fmaf(-2.f, dot, psq)));
    __syncthreads();

    float4* __restrict__ xm = reinterpret_cast<float4*>(xmat + base * P_N);
    #pragma unroll 8
    for (int i = 0; i < 128; ++i) {
        const int j = i * 256 + t;
        const float d = sdist[j >> 7];
        xm[j] = make_float4(d, d, d, d);
    }
    const float4 wv = reinterpret_cast<const float4*>(ws + 40)[t & 63];
    const float4 bv = reinterpret_cast<const float4*>(b)[t & 63];
    float4* __restrict__ om = reinterpret_cast<float4*>(outp + base * O_N);
    #pragma unroll 8
    for (int i = 0; i < 64; ++i) {
        const int j = i * 256 + t;
        const float d = sdist[j >> 6];
        om[j] = make_float4(fmaf(d, wv.x, bv.x), fmaf(d, wv.y, bv.y),
                            fmaf(d, wv.z, bv.z), fmaf(d, wv.w, bv.w));
    }
}

extern "C" void kernel_launch(void* const* d_in, const int* in_sizes, int n_in,
                              void* d_out, int out_size, void* d_ws, size_t ws_size,
                              hipStream_t stream) {
    const float* inp   = (const float*)d_in[0];
    const float* proto = (const float*)d_in[1];
    const float* W     = (const float*)d_in[2];
    const float* b     = (const float*)d_in[3];
    float* ws   = (float*)d_ws;
    float* xmat = (float*)d_out;
    float* outp = xmat + (long)B_ROWS * P_N;

    hipLaunchKernelGGL(pre_kernel, dim3(296), dim3(256), 0, stream, proto, W, ws);

    if (ws_size >= (size_t)(512 + B_ROWS + 64) * sizeof(float)) {
        float* dist = ws + 512;
        hipLaunchKernelGGL(dist_kernel, dim3(B_ROWS / 256), dim3(256), 0, stream,
                           inp, ws, dist);
        hipLaunchKernelGGL(stream_kernel, dim3(B_ROWS / 128), dim3(256), 0, stream,
                           b, ws, dist, xmat, outp);
    } else {
        hipLaunchKernelGGL(fused_kernel, dim3(B_ROWS / 256), dim3(256), 0, stream,
                           inp, b, ws, xmat, outp);
    }
}